// Round 1
// baseline (98.002 us; speedup 1.0000x reference)
//
#include <hip/hip_runtime.h>

#define TILE 128
#define DD 64

typedef short short8 __attribute__((ext_vector_type(8)));
typedef float f32x4 __attribute__((ext_vector_type(4)));
typedef unsigned short us4 __attribute__((ext_vector_type(4)));

__device__ __forceinline__ unsigned short f2bf(float x) {
    union { float f; unsigned u; } v; v.f = x;
    unsigned r = (v.u + 0x7FFFu + ((v.u >> 16) & 1u)) >> 16;   // RNE, no NaN inputs
    return (unsigned short)r;
}
__device__ __forceinline__ float bf2f(unsigned short h) {
    union { unsigned u; float f; } v; v.u = ((unsigned)h) << 16;
    return v.f;
}

__global__ __launch_bounds__(256) void sqexp_kernel(
    const float* __restrict__ X1, const float* __restrict__ X2,
    const float* __restrict__ lp, const float* __restrict__ sfp,
    float* __restrict__ out, int N, int M)
{
    // hi/lo bf16 split tiles, XOR-swizzled rows (row stride 128B -> bank conflict otherwise)
    __shared__ unsigned short A_hi[TILE*DD], A_lo[TILE*DD], B_hi[TILE*DD], B_lo[TILE*DD];
    __shared__ float sq1[TILE], sq2[TILE];

    const int t  = threadIdx.x;
    const int n0 = blockIdx.y * TILE;
    const int m0 = blockIdx.x * TILE;

    // ---- stage both tiles: fp32 -> (hi,lo) bf16 in LDS + per-row sum of squares ----
    for (int which = 0; which < 2; ++which) {
        const float4* src = (const float4*)(which ? (X2 + (size_t)m0 * DD)
                                                  : (X1 + (size_t)n0 * DD));
        unsigned short* hi = which ? B_hi : A_hi;
        unsigned short* lo = which ? B_lo : A_lo;
        float* sq          = which ? sq2  : sq1;
        #pragma unroll
        for (int i = 0; i < 8; ++i) {
            int idx  = i * 256 + t;          // float4 index within 128x64 tile
            float4 f = src[idx];
            int row  = idx >> 4;             // 16 float4 per row
            int slot = idx & 15;
            float part = f.x*f.x + f.y*f.y + f.z*f.z + f.w*f.w;
            part += __shfl_xor(part, 1);
            part += __shfl_xor(part, 2);
            part += __shfl_xor(part, 4);
            part += __shfl_xor(part, 8);     // 16 lanes share a row
            if ((t & 15) == 0) sq[row] = part;

            unsigned short h0 = f2bf(f.x), h1 = f2bf(f.y), h2 = f2bf(f.z), h3 = f2bf(f.w);
            unsigned short g0 = f2bf(f.x - bf2f(h0)), g1 = f2bf(f.y - bf2f(h1));
            unsigned short g2 = f2bf(f.z - bf2f(h2)), g3 = f2bf(f.w - bf2f(h3));
            int byte = row * 128 + slot * 8;
            byte ^= (row & 7) << 4;          // XOR swizzle (16B-chunk bijection)
            us4 hv = { h0, h1, h2, h3 };
            us4 gv = { g0, g1, g2, g3 };
            *(us4*)&hi[byte >> 1] = hv;
            *(us4*)&lo[byte >> 1] = gv;
        }
    }
    __syncthreads();

    // ---- MFMA compute: cross = hi.hi + hi.lo + lo.hi (fp32 accumulate) ----
    const int w  = t >> 6;                  // wave 0..3 in 2x2 grid
    const int l  = t & 63;
    const int wr = (w >> 1) * 64;
    const int wc = (w & 1) * 64;

    f32x4 acc[4][4] = {};
    #pragma unroll
    for (int ks = 0; ks < 2; ++ks) {
        const int kchunk = ks * 64 + ((l >> 4) * 16);   // byte offset of this lane's 8 bf16
        short8 ah[4], al[4], bh[4], bl[4];
        #pragma unroll
        for (int fm = 0; fm < 4; ++fm) {
            int row  = wr + fm * 16 + (l & 15);
            int byte = (row * 128 + kchunk) ^ ((row & 7) << 4);
            ah[fm] = *(const short8*)&A_hi[byte >> 1];
            al[fm] = *(const short8*)&A_lo[byte >> 1];
        }
        #pragma unroll
        for (int fn = 0; fn < 4; ++fn) {
            int row  = wc + fn * 16 + (l & 15);
            int byte = (row * 128 + kchunk) ^ ((row & 7) << 4);
            bh[fn] = *(const short8*)&B_hi[byte >> 1];
            bl[fn] = *(const short8*)&B_lo[byte >> 1];
        }
        #pragma unroll
        for (int fm = 0; fm < 4; ++fm)
            #pragma unroll
            for (int fn = 0; fn < 4; ++fn) {
                acc[fm][fn] = __builtin_amdgcn_mfma_f32_16x16x32_bf16(ah[fm], bh[fn], acc[fm][fn], 0, 0, 0);
                acc[fm][fn] = __builtin_amdgcn_mfma_f32_16x16x32_bf16(ah[fm], bl[fn], acc[fm][fn], 0, 0, 0);
                acc[fm][fn] = __builtin_amdgcn_mfma_f32_16x16x32_bf16(al[fm], bh[fn], acc[fm][fn], 0, 0, 0);
            }
    }

    // ---- fused epilogue: dist -> clamp -> exp -> store ----
    const float lv   = lp[0], sf = sfp[0];
    const float ninv = -0.5f / (lv * lv);
    const float amp  = sf * sf;

    #pragma unroll
    for (int fm = 0; fm < 4; ++fm) {
        #pragma unroll
        for (int fn = 0; fn < 4; ++fn) {
            int colL  = wc + fn * 16 + (l & 15);
            float s2  = sq2[colL];
            #pragma unroll
            for (int r = 0; r < 4; ++r) {
                int rowL   = wr + fm * 16 + (l >> 4) * 4 + r;   // C/D: col=lane&15, row=(lane>>4)*4+r
                float dist = sq1[rowL] + s2 - 2.0f * acc[fm][fn][r];
                dist = fmaxf(dist, 0.0f);
                out[(size_t)(n0 + rowL) * M + (m0 + colL)] = amp * __expf(ninv * dist);
            }
        }
    }
}

extern "C" void kernel_launch(void* const* d_in, const int* in_sizes, int n_in,
                              void* d_out, int out_size, void* d_ws, size_t ws_size,
                              hipStream_t stream) {
    const float* X1 = (const float*)d_in[0];
    const float* X2 = (const float*)d_in[1];
    const float* lp = (const float*)d_in[2];
    const float* sf = (const float*)d_in[3];
    float* out = (float*)d_out;
    const int N = in_sizes[0] / DD;
    const int M = in_sizes[1] / DD;
    dim3 grid(M / TILE, N / TILE);
    sqexp_kernel<<<grid, 256, 0, stream>>>(X1, X2, lp, sf, out, N, M);
}